// Round 5
// baseline (17863.889 us; speedup 1.0000x reference)
//
#include <hip/hip_runtime.h>

#define B_    1024
#define T_    512
#define I_    16
#define H_    50
#define FC_   64
#define HALFW 28    // half of padded H
#define HP    56    // padded H for float4 reads

__device__ __forceinline__ float sigm(float x)   { return 1.0f / (1.0f + __expf(-x)); }
__device__ __forceinline__ float tanh_f(float x) { return 1.0f - 2.0f / (1.0f + __expf(2.0f * x)); }

// 2 batch rows per block. Lane layout (tid < 400): tid = 8*u + 2*q + s.
// SOFTWARE-PIPELINED: tick k computes layer0 step k AND layer1 step k-1 in one
// phase -> 1 barrier/tick, h0 read once feeds both layers, 2x ILP on the
// shuffle/activation chains. 513 ticks total.
__global__ __launch_bounds__(448) __attribute__((amdgpu_waves_per_eu(4)))
void lstm_fused5(
    const float* __restrict__ x,
    const float* __restrict__ w_ih0, const float* __restrict__ w_hh0,
    const float* __restrict__ b_ih0, const float* __restrict__ b_hh0,
    const float* __restrict__ w_ih1, const float* __restrict__ w_hh1,
    const float* __restrict__ b_ih1, const float* __restrict__ b_hh1,
    const float* __restrict__ fc1_w, const float* __restrict__ fc1_b,
    const float* __restrict__ fc2_w, const float* __restrict__ fc2_b,
    float* __restrict__ out)
{
    __shared__ float h0s[2][2][HP], h1s[2][2][HP];   // [parity][row][HP]
    __shared__ float xs[4][2][I_];                   // prefetch ring, distance 2

    const int tid  = threadIdx.x;
    const int row0 = blockIdx.x * 2;
    const int u    = tid >> 3;
    const int q    = (tid >> 1) & 3;
    const int s    = tid & 1;
    const bool gl  = tid < 400;
    const int uc   = (u < H_) ? u : (H_ - 1);
    const int g    = q * H_ + uc;
    const int base = tid & ~7;

    // ---- persistent weights: 8 + 3*28 = 92 floats ----
    float w0x[8], w0h[HALFW], w1x[HALFW], w1h[HALFW];
    #pragma unroll
    for (int i = 0; i < 8; ++i) w0x[i] = w_ih0[g * I_ + s * 8 + i];
    #pragma unroll
    for (int j = 0; j < HALFW; ++j) {
        const int jj = s * HALFW + j;
        const bool v = jj < H_;
        w0h[j] = v ? w_hh0[g * H_ + jj] : 0.f;
        w1x[j] = v ? w_ih1[g * H_ + jj] : 0.f;
        w1h[j] = v ? w_hh1[g * H_ + jj] : 0.f;
    }
    float bias0 = (s == 0) ? (b_ih0[g] + b_hh0[g]) : 0.f;
    float bias1 = (s == 0) ? (b_ih1[g] + b_hh1[g]) : 0.f;

    if (tid < 2 * 2 * HP) {                          // zero both parities
        ((float*)h0s)[tid] = 0.f;
        ((float*)h1s)[tid] = 0.f;
    }
    if (tid < 16) {                                  // stage x(0), x(1)
        const int tt = tid >> 3, r = (tid >> 2) & 1, i4 = (tid & 3) * 4;
        *(float4*)&xs[tt][r][i4] =
            *(const float4*)(x + ((size_t)(row0 + r) * T_ + tt) * I_ + i4);
    }
    float c00 = 0.f, c01 = 0.f, c10 = 0.f, c11 = 0.f;  // c[layer][row]
    __syncthreads();

    // tick k: L0 computes step k (k<T), L1 computes step k-1 (k>=1).
    for (int k = 0; k <= T_; ++k) {
        const int pr = (k + 1) & 1;                  // parity of h0[k-1] / read side

        if (gl) {
            float a0 = bias0, a1 = bias0;            // L0 pre-acts, rows 0/1
            float b0 = bias1, b1 = bias1;            // L1 pre-acts, rows 0/1

            // x part (L0, step k)
            {
                const float4* xp0 = (const float4*)(xs[k & 3][0] + s * 8);
                const float4* xp1 = (const float4*)(xs[k & 3][1] + s * 8);
                float4 v00 = xp0[0], v01 = xp0[1], v10 = xp1[0], v11 = xp1[1];
                a0 += w0x[0]*v00.x + w0x[1]*v00.y + w0x[2]*v00.z + w0x[3]*v00.w
                    + w0x[4]*v01.x + w0x[5]*v01.y + w0x[6]*v01.z + w0x[7]*v01.w;
                a1 += w0x[0]*v10.x + w0x[1]*v10.y + w0x[2]*v10.z + w0x[3]*v10.w
                    + w0x[4]*v11.x + w0x[5]*v11.y + w0x[6]*v11.z + w0x[7]*v11.w;
            }

            // shared h0[k-1] read feeds BOTH w0h (L0) and w1x (L1)
            {
                const float4* h00 = (const float4*)(h0s[pr][0] + s * HALFW);
                const float4* h01 = (const float4*)(h0s[pr][1] + s * HALFW);
                #pragma unroll
                for (int kk = 0; kk < 7; ++kk) {
                    float4 hv0 = h00[kk], hv1 = h01[kk];
                    a0 += w0h[4*kk]*hv0.x + w0h[4*kk+1]*hv0.y + w0h[4*kk+2]*hv0.z + w0h[4*kk+3]*hv0.w;
                    a1 += w0h[4*kk]*hv1.x + w0h[4*kk+1]*hv1.y + w0h[4*kk+2]*hv1.z + w0h[4*kk+3]*hv1.w;
                    b0 += w1x[4*kk]*hv0.x + w1x[4*kk+1]*hv0.y + w1x[4*kk+2]*hv0.z + w1x[4*kk+3]*hv0.w;
                    b1 += w1x[4*kk]*hv1.x + w1x[4*kk+1]*hv1.y + w1x[4*kk+2]*hv1.z + w1x[4*kk+3]*hv1.w;
                }
            }
            // h1[k-2] part (L1 recurrent)
            {
                const float4* h10 = (const float4*)(h1s[k & 1][0] + s * HALFW);
                const float4* h11 = (const float4*)(h1s[k & 1][1] + s * HALFW);
                #pragma unroll
                for (int kk = 0; kk < 7; ++kk) {
                    float4 hv0 = h10[kk], hv1 = h11[kk];
                    b0 += w1h[4*kk]*hv0.x + w1h[4*kk+1]*hv0.y + w1h[4*kk+2]*hv0.z + w1h[4*kk+3]*hv0.w;
                    b1 += w1h[4*kk]*hv1.x + w1h[4*kk+1]*hv1.y + w1h[4*kk+2]*hv1.z + w1h[4*kk+3]*hv1.w;
                }
            }

            // two independent reduce/act/broadcast chains (ILP)
            a0 += __shfl_xor(a0, 1);  a1 += __shfl_xor(a1, 1);
            b0 += __shfl_xor(b0, 1);  b1 += __shfl_xor(b1, 1);
            const float actA0 = (q == 2) ? tanh_f(a0) : sigm(a0);
            const float actA1 = (q == 2) ? tanh_f(a1) : sigm(a1);
            const float actB0 = (q == 2) ? tanh_f(b0) : sigm(b0);
            const float actB1 = (q == 2) ? tanh_f(b1) : sigm(b1);

            const float iA0 = __shfl(actA0, base),     iA1 = __shfl(actA1, base);
            const float fA0 = __shfl(actA0, base + 2), fA1 = __shfl(actA1, base + 2);
            const float gA0 = __shfl(actA0, base + 4), gA1 = __shfl(actA1, base + 4);
            const float oA0 = __shfl(actA0, base + 6), oA1 = __shfl(actA1, base + 6);
            const float iB0 = __shfl(actB0, base),     iB1 = __shfl(actB1, base);
            const float fB0 = __shfl(actB0, base + 2), fB1 = __shfl(actB1, base + 2);
            const float gB0 = __shfl(actB0, base + 4), gB1 = __shfl(actB1, base + 4);
            const float oB0 = __shfl(actB0, base + 6), oB1 = __shfl(actB1, base + 6);

            // L0 commit (k==T writes dead state; harmless, buffer unread)
            c00 = fA0 * c00 + iA0 * gA0;
            c01 = fA1 * c01 + iA1 * gA1;
            if ((tid & 7) == 0) {
                h0s[k & 1][0][u] = oA0 * tanh_f(c00);
                h0s[k & 1][1][u] = oA1 * tanh_f(c01);
            }
            // L1 commit: step k-1, guarded (c1 must stay clean at k=0)
            if (k >= 1) {
                c10 = fB0 * c10 + iB0 * gB0;
                c11 = fB1 * c11 + iB1 * gB1;
                if ((tid & 7) == 0) {
                    h1s[(k - 1) & 1][0][u] = oB0 * tanh_f(c10);
                    h1s[(k - 1) & 1][1][u] = oB1 * tanh_f(c11);
                }
            }
        } else if (tid >= 416 && tid < 424) {
            if (k + 2 < T_) {
                const int idx = tid - 416, r = idx >> 2, i4 = (idx & 3) * 4;
                *(float4*)&xs[(k + 2) & 3][r][i4] =
                    *(const float4*)(x + ((size_t)(row0 + r) * T_ + k + 2) * I_ + i4);
            }
        }
        __syncthreads();
    }

    // ---- FC epilogue: final h1 = step T-1 -> parity (T-1)&1 = 1 ----
    if (tid < 2 * FC_) {
        const int r = tid >> 6, uu = tid & 63;
        const float* hf = h1s[1][r];
        float a = fc1_b[uu];
        #pragma unroll
        for (int j = 0; j < H_; ++j) a += fc1_w[uu * H_ + j] * hf[j];
        float rsum = fmaxf(a, 0.f) * fc2_w[uu];
        #pragma unroll
        for (int off = 1; off < FC_; off <<= 1) rsum += __shfl_xor(rsum, off);
        if (uu == 0) out[row0 + r] = rsum + fc2_b[0];
    }
}

extern "C" void kernel_launch(void* const* d_in, const int* in_sizes, int n_in,
                              void* d_out, int out_size, void* d_ws, size_t ws_size,
                              hipStream_t stream) {
    const float* x     = (const float*)d_in[0];
    const float* w_ih0 = (const float*)d_in[1];
    const float* w_hh0 = (const float*)d_in[2];
    const float* b_ih0 = (const float*)d_in[3];
    const float* b_hh0 = (const float*)d_in[4];
    const float* w_ih1 = (const float*)d_in[5];
    const float* w_hh1 = (const float*)d_in[6];
    const float* b_ih1 = (const float*)d_in[7];
    const float* b_hh1 = (const float*)d_in[8];
    const float* fc1_w = (const float*)d_in[9];
    const float* fc1_b = (const float*)d_in[10];
    const float* fc2_w = (const float*)d_in[11];
    const float* fc2_b = (const float*)d_in[12];
    float* out = (float*)d_out;

    dim3 grid(B_ / 2), block(448);
    hipLaunchKernelGGL(lstm_fused5, grid, block, 0, stream,
                       x, w_ih0, w_hh0, b_ih0, b_hh0,
                       w_ih1, w_hh1, b_ih1, b_hh1,
                       fc1_w, fc1_b, fc2_w, fc2_b, out);
}

// Round 6
// 17119.579 us; speedup vs baseline: 1.0435x; 1.0435x over previous
//
#include <hip/hip_runtime.h>

#define B_    1024
#define T_    512
#define I_    16
#define H_    50
#define FC_   64
#define HALFW 28    // half of padded H
#define HP    56    // padded H for float4 reads

__device__ __forceinline__ float sigm(float x)   { return 1.0f / (1.0f + __expf(-x)); }
__device__ __forceinline__ float tanh_f(float x) { return 1.0f - 2.0f / (1.0f + __expf(2.0f * x)); }

// 2 batch rows per block. Lane layout (tid < 400): tid = 8*u + 2*q + s.
// Weights pinned in VGPRs via opaque volatile asm (R4-proven: defeats
// remat/sink; worst case is scratch spill, never global re-fetch).
// waves_per_eu(4,4): target exactly 128 VGPR so TWO 7-wave blocks fit per CU
// (512 VGPR/SIMD pool; 14 waves -> 4 on some SIMDs -> need <=128).
// x prefetch is ASYNC: load lands in a register one tick early; the tick only
// ds_writes the already-arrived value, so no VMEM round-trip on the barrier path.
__global__ __launch_bounds__(448) __attribute__((amdgpu_waves_per_eu(4, 4)))
void lstm_fused6(
    const float* __restrict__ x,
    const float* __restrict__ w_ih0, const float* __restrict__ w_hh0,
    const float* __restrict__ b_ih0, const float* __restrict__ b_hh0,
    const float* __restrict__ w_ih1, const float* __restrict__ w_hh1,
    const float* __restrict__ b_ih1, const float* __restrict__ b_hh1,
    const float* __restrict__ fc1_w, const float* __restrict__ fc1_b,
    const float* __restrict__ fc2_w, const float* __restrict__ fc2_b,
    float* __restrict__ out)
{
    __shared__ float h0s[2][2][HP], h1s[2][2][HP];   // [parity][row][HP]
    __shared__ float xs[4][2][I_];                   // prefetch ring, distance 2

    const int tid  = threadIdx.x;
    const int row0 = blockIdx.x * 2;
    const int u    = tid >> 3;
    const int q    = (tid >> 1) & 3;
    const int s    = tid & 1;
    const bool gl  = tid < 400;
    const int uc   = (u < H_) ? u : (H_ - 1);        // clamp for lanes >= 400
    const int g    = q * H_ + uc;
    const int base = tid & ~7;

    // ---- persistent weights: 8 + 3*28 = 92 floats, loaded unconditionally ----
    float w0x[8], w0h[HALFW], w1x[HALFW], w1h[HALFW];
    #pragma unroll
    for (int i = 0; i < 8; ++i) w0x[i] = w_ih0[g * I_ + s * 8 + i];
    #pragma unroll
    for (int j = 0; j < HALFW; ++j) {
        const int jj = s * HALFW + j;
        const bool v = jj < H_;
        w0h[j] = v ? w_hh0[g * H_ + jj] : 0.f;
        w1x[j] = v ? w_ih1[g * H_ + jj] : 0.f;
        w1h[j] = v ? w_hh1[g * H_ + jj] : 0.f;
    }
    float bias0 = (s == 0) ? (b_ih0[g] + b_hh0[g]) : 0.f;
    float bias1 = (s == 0) ? (b_ih1[g] + b_hh1[g]) : 0.f;

    // ---- pin in registers: opaque to LICM/remat/sink ----
    #pragma unroll
    for (int i = 0; i < 8; ++i) asm volatile("" : "+v"(w0x[i]));
    #pragma unroll
    for (int j = 0; j < HALFW; ++j) {
        asm volatile("" : "+v"(w0h[j]));
        asm volatile("" : "+v"(w1x[j]));
        asm volatile("" : "+v"(w1h[j]));
    }
    asm volatile("" : "+v"(bias0));
    asm volatile("" : "+v"(bias1));

    if (tid < 2 * 2 * HP) {                          // zero h incl. padding
        ((float*)h0s)[tid] = 0.f;
        ((float*)h1s)[tid] = 0.f;
    }
    // async x pipeline: lanes 400..407 own one float4 of (row r, chunk j)
    float4 xreg = make_float4(0.f, 0.f, 0.f, 0.f);
    if (tid >= 400 && tid < 408) {
        const int idx = tid - 400, r = idx >> 2, j4 = (idx & 3) * 4;
        const float* xb = x + (size_t)(row0 + r) * T_ * I_ + j4;
        *(float4*)&xs[0][r][j4] = *(const float4*)(xb + 0 * I_);
        *(float4*)&xs[1][r][j4] = *(const float4*)(xb + 1 * I_);
        *(float4*)&xs[2][r][j4] = *(const float4*)(xb + 2 * I_);
        xreg = *(const float4*)(xb + 3 * I_);        // for tick 3
    }
    float c00 = 0.f, c01 = 0.f, c10 = 0.f, c11 = 0.f;  // c[layer][row]
    __syncthreads();

    for (int t = 0; t < T_; ++t) {
        const int p = t & 1;                         // read h*[p], write h*[1-p]

        // ---- P0: layer-0 gates + cell update ----
        if (gl) {
            float a0 = bias0, a1 = bias0;
            const float4* xp0 = (const float4*)(xs[t & 3][0] + s * 8);
            const float4* xp1 = (const float4*)(xs[t & 3][1] + s * 8);
            float4 v00 = xp0[0], v01 = xp0[1], v10 = xp1[0], v11 = xp1[1];
            a0 += w0x[0]*v00.x + w0x[1]*v00.y + w0x[2]*v00.z + w0x[3]*v00.w
                + w0x[4]*v01.x + w0x[5]*v01.y + w0x[6]*v01.z + w0x[7]*v01.w;
            a1 += w0x[0]*v10.x + w0x[1]*v10.y + w0x[2]*v10.z + w0x[3]*v10.w
                + w0x[4]*v11.x + w0x[5]*v11.y + w0x[6]*v11.z + w0x[7]*v11.w;
            const float4* h00 = (const float4*)(h0s[p][0] + s * HALFW);
            const float4* h01 = (const float4*)(h0s[p][1] + s * HALFW);
            #pragma unroll
            for (int k = 0; k < 7; ++k) {
                float4 a = h00[k], b = h01[k];
                a0 += w0h[4*k]*a.x + w0h[4*k+1]*a.y + w0h[4*k+2]*a.z + w0h[4*k+3]*a.w;
                a1 += w0h[4*k]*b.x + w0h[4*k+1]*b.y + w0h[4*k+2]*b.z + w0h[4*k+3]*b.w;
            }
            a0 += __shfl_xor(a0, 1);
            a1 += __shfl_xor(a1, 1);
            const float act0 = (q == 2) ? tanh_f(a0) : sigm(a0);
            const float act1 = (q == 2) ? tanh_f(a1) : sigm(a1);
            const float gi0 = __shfl(act0, base),     gi1 = __shfl(act1, base);
            const float gf0 = __shfl(act0, base + 2), gf1 = __shfl(act1, base + 2);
            const float gg0 = __shfl(act0, base + 4), gg1 = __shfl(act1, base + 4);
            const float go0 = __shfl(act0, base + 6), go1 = __shfl(act1, base + 6);
            c00 = gf0 * c00 + gi0 * gg0;
            c01 = gf1 * c01 + gi1 * gg1;
            if ((tid & 7) == 0) {
                h0s[1 - p][0][u] = go0 * tanh_f(c00);
                h0s[1 - p][1][u] = go1 * tanh_f(c01);
            }
        } else if (tid >= 400 && tid < 408) {
            // write value loaded LAST tick (already landed), then issue next load
            const int idx = tid - 400, r = idx >> 2, j4 = (idx & 3) * 4;
            if (t + 3 <= T_) {                       // slot for tick t+2 valid while t+2<T... t+2<=T_-1
                if (t + 2 < T_)
                    *(float4*)&xs[(t + 2) & 3][r][j4] = xreg;
                const int tn = (t + 3 < T_) ? (t + 3) : (T_ - 1);
                xreg = *(const float4*)(x + ((size_t)(row0 + r) * T_ + tn) * I_ + j4);
            }
        }
        __syncthreads();

        // ---- P1: layer-1 gates + cell update ----
        if (gl) {
            float a0 = bias1, a1 = bias1;
            const float4* g00 = (const float4*)(h0s[1 - p][0] + s * HALFW);
            const float4* g01 = (const float4*)(h0s[1 - p][1] + s * HALFW);
            const float4* g10 = (const float4*)(h1s[p][0]     + s * HALFW);
            const float4* g11 = (const float4*)(h1s[p][1]     + s * HALFW);
            #pragma unroll
            for (int k = 0; k < 7; ++k) {
                float4 a = g00[k], b = g01[k];
                a0 += w1x[4*k]*a.x + w1x[4*k+1]*a.y + w1x[4*k+2]*a.z + w1x[4*k+3]*a.w;
                a1 += w1x[4*k]*b.x + w1x[4*k+1]*b.y + w1x[4*k+2]*b.z + w1x[4*k+3]*b.w;
            }
            #pragma unroll
            for (int k = 0; k < 7; ++k) {
                float4 a = g10[k], b = g11[k];
                a0 += w1h[4*k]*a.x + w1h[4*k+1]*a.y + w1h[4*k+2]*a.z + w1h[4*k+3]*a.w;
                a1 += w1h[4*k]*b.x + w1h[4*k+1]*b.y + w1h[4*k+2]*b.z + w1h[4*k+3]*b.w;
            }
            a0 += __shfl_xor(a0, 1);
            a1 += __shfl_xor(a1, 1);
            const float act0 = (q == 2) ? tanh_f(a0) : sigm(a0);
            const float act1 = (q == 2) ? tanh_f(a1) : sigm(a1);
            const float gi0 = __shfl(act0, base),     gi1 = __shfl(act1, base);
            const float gf0 = __shfl(act0, base + 2), gf1 = __shfl(act1, base + 2);
            const float gg0 = __shfl(act0, base + 4), gg1 = __shfl(act1, base + 4);
            const float go0 = __shfl(act0, base + 6), go1 = __shfl(act1, base + 6);
            c10 = gf0 * c10 + gi0 * gg0;
            c11 = gf1 * c11 + gi1 * gg1;
            if ((tid & 7) == 0) {
                h1s[1 - p][0][u] = go0 * tanh_f(c10);
                h1s[1 - p][1][u] = go1 * tanh_f(c11);
            }
        }
        __syncthreads();
    }

    // ---- FC epilogue: final h1 in h1s[0][r] (T even). Row r on wave r. ----
    if (tid < 2 * FC_) {
        const int r = tid >> 6, uu = tid & 63;
        const float* hf = h1s[0][r];
        float a = fc1_b[uu];
        #pragma unroll
        for (int j = 0; j < H_; ++j) a += fc1_w[uu * H_ + j] * hf[j];
        float rsum = fmaxf(a, 0.f) * fc2_w[uu];
        #pragma unroll
        for (int off = 1; off < FC_; off <<= 1) rsum += __shfl_xor(rsum, off);
        if (uu == 0) out[row0 + r] = rsum + fc2_b[0];
    }
}

extern "C" void kernel_launch(void* const* d_in, const int* in_sizes, int n_in,
                              void* d_out, int out_size, void* d_ws, size_t ws_size,
                              hipStream_t stream) {
    const float* x     = (const float*)d_in[0];
    const float* w_ih0 = (const float*)d_in[1];
    const float* w_hh0 = (const float*)d_in[2];
    const float* b_ih0 = (const float*)d_in[3];
    const float* b_hh0 = (const float*)d_in[4];
    const float* w_ih1 = (const float*)d_in[5];
    const float* w_hh1 = (const float*)d_in[6];
    const float* b_ih1 = (const float*)d_in[7];
    const float* b_hh1 = (const float*)d_in[8];
    const float* fc1_w = (const float*)d_in[9];
    const float* fc1_b = (const float*)d_in[10];
    const float* fc2_w = (const float*)d_in[11];
    const float* fc2_b = (const float*)d_in[12];
    float* out = (float*)d_out;

    dim3 grid(B_ / 2), block(448);
    hipLaunchKernelGGL(lstm_fused6, grid, block, 0, stream,
                       x, w_ih0, w_hh0, b_ih0, b_hh0,
                       w_ih1, w_hh1, b_ih1, b_hh1,
                       fc1_w, fc1_b, fc2_w, fc2_b, out);
}